// Round 8
// baseline (396.958 us; speedup 1.0000x reference)
//
#include <hip/hip_runtime.h>
#include <hip/hip_bf16.h>

#define N_NODES 100000
#define N_EDGES 1600000
#define F_IN 128
#define F_HID 256
#define F_OUT 128

typedef unsigned short ushort_t;
typedef __attribute__((ext_vector_type(4))) float f32x4;
typedef __attribute__((ext_vector_type(8))) short bf16x8;

#define GAS __attribute__((address_space(1)))
#define LAS __attribute__((address_space(3)))

__device__ __forceinline__ float bf2f(ushort_t u) {
    unsigned int x = ((unsigned int)u) << 16;
    return __builtin_bit_cast(float, x);
}
__device__ __forceinline__ ushort_t f2bf(float f) {
    unsigned int x = __builtin_bit_cast(unsigned int, f);
    unsigned int r = (x + 0x7fffu + ((x >> 16) & 1u)) >> 16;
    return (ushort_t)r;
}

// ---------------- CSR build ----------------
__global__ __launch_bounds__(256) void deg_count_kernel(const int* __restrict__ dst,
                                                        int* __restrict__ cnt, int n) {
    int i = blockIdx.x * 256 + threadIdx.x;
    if (i < n) atomicAdd(&cnt[__builtin_nontemporal_load(dst + i)], 1);
}

__global__ __launch_bounds__(256) void invdeg_kernel(const int* __restrict__ cnt,
                                                     float* __restrict__ inv, int n) {
    int i = blockIdx.x * 256 + threadIdx.x;
    if (i < n) inv[i] = 1.0f / fmaxf((float)cnt[i], 1.0f);
}

__global__ __launch_bounds__(1024) void scan1_kernel(const int* __restrict__ cnt,
                                                     int* __restrict__ rowptr,
                                                     int* __restrict__ blockSums, int n) {
    __shared__ int tmp[1024];
    int tid = threadIdx.x;
    int i = blockIdx.x * 1024 + tid;
    int v = (i < n) ? cnt[i] : 0;
    tmp[tid] = v;
    __syncthreads();
#pragma unroll
    for (int off = 1; off < 1024; off <<= 1) {
        int t = (tid >= off) ? tmp[tid - off] : 0;
        __syncthreads();
        tmp[tid] += t;
        __syncthreads();
    }
    if (i < n) rowptr[i] = tmp[tid] - v;
    if (tid == 1023) blockSums[blockIdx.x] = tmp[1023];
}

__global__ __launch_bounds__(128) void scan2_kernel(int* __restrict__ blockSums, int nb) {
    __shared__ int tmp[128];
    int tid = threadIdx.x;
    int v = (tid < nb) ? blockSums[tid] : 0;
    tmp[tid] = v;
    __syncthreads();
#pragma unroll
    for (int off = 1; off < 128; off <<= 1) {
        int t = (tid >= off) ? tmp[tid - off] : 0;
        __syncthreads();
        tmp[tid] += t;
        __syncthreads();
    }
    if (tid < nb) blockSums[tid] = tmp[tid] - v;
}

__global__ __launch_bounds__(1024) void scan3_kernel(int* __restrict__ rowptr,
                                                     int* __restrict__ cursor,
                                                     const int* __restrict__ blockSums, int n) {
    int i = blockIdx.x * 1024 + threadIdx.x;
    if (i < n) {
        int v = rowptr[i] + blockSums[blockIdx.x];
        rowptr[i] = v;
        cursor[i] = v;
    }
    if (i == 0) rowptr[n] = N_EDGES;
}

// XCD-pinned fill with NON-TEMPORAL streaming reads. Round-7 evidence: the
// 6.4MB/pass dst stream thrashed the ~800KB of accumulating csr_src lines in
// L2 (72MB HBM writes for 6.4MB of data). NT loads keep the stream from
// evicting the write lines.
#define XBANDS 8
#define BAND_SZ (N_NODES / XBANDS)  // 12500
__global__ __launch_bounds__(256) void fill_csr_xcd_kernel(
    const int* __restrict__ src, const int* __restrict__ dst,
    int* __restrict__ cursor, int* __restrict__ csr_src, int n) {
    int band = blockIdx.x & 7;
    int i = (blockIdx.x >> 3) * 256 + threadIdx.x;
    if (i >= n) return;
    int d = __builtin_nontemporal_load(dst + i);
    if (d >= band * BAND_SZ && d < (band + 1) * BAND_SZ) {
        int s = __builtin_nontemporal_load(src + i);
        int p = atomicAdd(&cursor[d], 1);
        csr_src[p] = s;
    }
}

// ---------------- fp32 -> bf16 converts ----------------
__global__ __launch_bounds__(256) void convert_x_kernel(const float* __restrict__ x,
                                                        ushort_t* __restrict__ A1, int n4) {
    int i = blockIdx.x * 256 + threadIdx.x;
    if (i >= n4) return;
    int e = i * 4;
    int row = e >> 7;
    int col = e & 127;
    f32x4 v = __builtin_nontemporal_load((const f32x4*)(x + (size_t)row * F_IN + col));
    ushort4 o;
    o.x = f2bf(v.x); o.y = f2bf(v.y); o.z = f2bf(v.z); o.w = f2bf(v.w);
    *(ushort4*)(A1 + (size_t)row * 256 + col) = o;
}

// Wt[n][k] = bf16( k<Kx ? W1[k][n] : W2[k-Kx][n] )  -- stack along K
__global__ __launch_bounds__(256) void wtransK_kernel(const float* __restrict__ W1,
                                                      const float* __restrict__ W2,
                                                      ushort_t* __restrict__ Wt,
                                                      int Kx, int Ktot, int N) {
    int i = blockIdx.x * 256 + threadIdx.x;
    if (i >= N * Ktot) return;
    int n = i / Ktot, k = i - n * Ktot;
    float v = (k < Kx) ? W1[(size_t)k * N + n] : W2[(size_t)(k - Kx) * N + n];
    Wt[(size_t)n * Ktot + k] = f2bf(v);
}

// Wt[n][k]: n<Nh -> Wa[k][n], else Wb[k][n-Nh]  -- stack along N
__global__ __launch_bounds__(256) void wtransN_kernel(const float* __restrict__ Wa,
                                                      const float* __restrict__ Wb,
                                                      ushort_t* __restrict__ Wt,
                                                      int K, int Nh) {
    int i = blockIdx.x * 256 + threadIdx.x;
    if (i >= 2 * Nh * K) return;
    int n = i / K, k = i - n * K;
    const float* W = (n < Nh) ? Wa : Wb;
    int nn = (n < Nh) ? n : n - Nh;
    Wt[(size_t)n * K + k] = f2bf(W[(size_t)k * Nh + nn]);
}

// ---------------- 16-lane-per-edge gather, 4 edges per group-iter ----------------
#define ACC8(v)                                                     \
    acc[0] += bf2f((ushort_t)((v).x & 0xffffu));                    \
    acc[1] += bf2f((ushort_t)((v).x >> 16));                        \
    acc[2] += bf2f((ushort_t)((v).y & 0xffffu));                    \
    acc[3] += bf2f((ushort_t)((v).y >> 16));                        \
    acc[4] += bf2f((ushort_t)((v).z & 0xffffu));                    \
    acc[5] += bf2f((ushort_t)((v).z >> 16));                        \
    acc[6] += bf2f((ushort_t)((v).w & 0xffffu));                    \
    acc[7] += bf2f((ushort_t)((v).w >> 16));

template <int MODE>
__global__ __launch_bounds__(256) void gather16_kernel(
    const ushort_t* __restrict__ H, int ldh,
    const int* __restrict__ rowptr, const int* __restrict__ csr_src,
    const float* __restrict__ invdeg,
    const ushort_t* __restrict__ uself, int ldu,
    const float* __restrict__ bias,
    void* __restrict__ outp, int ldo, int nNodes) {
    int lane = threadIdx.x & 63;
    int node = blockIdx.x * 4 + (threadIdx.x >> 6);
    if (node >= nNodes) return;
    int grp = lane >> 4, sub = lane & 15;
    int start = rowptr[node], end = rowptr[node + 1];
    const size_t cofs = (size_t)sub * 8;
    float acc[8] = {};
    // 16 edges in flight per wave: 4 groups x 4 predicated loads
    for (int e = start + grp; e < end; e += 16) {
        int s0 = csr_src[e];
        uint4 v0 = *(const uint4*)(H + (size_t)s0 * ldh + cofs);
        bool p1 = (e + 4) < end;
        int s1 = p1 ? csr_src[e + 4] : s0;
        uint4 v1 = *(const uint4*)(H + (size_t)s1 * ldh + cofs);
        bool p2 = (e + 8) < end;
        int s2 = p2 ? csr_src[e + 8] : s0;
        uint4 v2 = *(const uint4*)(H + (size_t)s2 * ldh + cofs);
        bool p3 = (e + 12) < end;
        int s3 = p3 ? csr_src[e + 12] : s0;
        uint4 v3 = *(const uint4*)(H + (size_t)s3 * ldh + cofs);
        ACC8(v0);
        if (p1) { ACC8(v1); }
        if (p2) { ACC8(v2); }
        if (p3) { ACC8(v3); }
    }
#pragma unroll
    for (int j = 0; j < 8; ++j) {
        acc[j] += __shfl_xor(acc[j], 16);
        acc[j] += __shfl_xor(acc[j], 32);
    }
    if (grp == 0) {
        float sc = invdeg[node];
        if (MODE == 0) {
            uint4 o;
            o.x = (unsigned)f2bf(acc[0] * sc) | ((unsigned)f2bf(acc[1] * sc) << 16);
            o.y = (unsigned)f2bf(acc[2] * sc) | ((unsigned)f2bf(acc[3] * sc) << 16);
            o.z = (unsigned)f2bf(acc[4] * sc) | ((unsigned)f2bf(acc[5] * sc) << 16);
            o.w = (unsigned)f2bf(acc[6] * sc) | ((unsigned)f2bf(acc[7] * sc) << 16);
            *(uint4*)((ushort_t*)outp + (size_t)node * ldo + cofs) = o;
        } else {
            uint4 us = *(const uint4*)(uself + (size_t)node * ldu + cofs);
            f32x4 o0, o1;
            o0.x = acc[0] * sc + bf2f((ushort_t)(us.x & 0xffffu)) + bias[cofs + 0];
            o0.y = acc[1] * sc + bf2f((ushort_t)(us.x >> 16)) + bias[cofs + 1];
            o0.z = acc[2] * sc + bf2f((ushort_t)(us.y & 0xffffu)) + bias[cofs + 2];
            o0.w = acc[3] * sc + bf2f((ushort_t)(us.y >> 16)) + bias[cofs + 3];
            o1.x = acc[4] * sc + bf2f((ushort_t)(us.z & 0xffffu)) + bias[cofs + 4];
            o1.y = acc[5] * sc + bf2f((ushort_t)(us.z >> 16)) + bias[cofs + 5];
            o1.z = acc[6] * sc + bf2f((ushort_t)(us.w & 0xffffu)) + bias[cofs + 6];
            o1.w = acc[7] * sc + bf2f((ushort_t)(us.w >> 16)) + bias[cofs + 7];
            float* op = (float*)outp + (size_t)node * ldo + cofs;
            __builtin_nontemporal_store(o0, (f32x4*)op);
            __builtin_nontemporal_store(o1, (f32x4*)(op + 4));
        }
    }
}

// ---------------- bf16 MFMA GEMM ----------------
// C = A[M][K] @ Bt[N][K]^T ; 128x128 tile, 4 waves x (64x64), BK=64.
// mode 0: bf16 out, +bias, sigmoid ; mode 1: bf16 out
// Epilogue: per-wave LDS transpose (XOR-swizzled, conflict-free) -> b128 stores.
__global__ __launch_bounds__(256) void gemm_mfma_kernel(
    const ushort_t* __restrict__ A,
    const ushort_t* __restrict__ Bt,
    const float* __restrict__ bias,
    ushort_t* __restrict__ Cout,
    int M, int N, int K, int mode) {
    __shared__ ushort_t shmem[2 * 128 * 64];  // staging As|Bs; reused by epilogue
    ushort_t* As = shmem;
    ushort_t* Bs = shmem + 128 * 64;
    int tid = threadIdx.x;
    int lane = tid & 63, wid = tid >> 6;
    int l15 = lane & 15, kgrp = lane >> 4, l7 = lane & 7, l8 = lane >> 3;
    int bm = blockIdx.x * 128, bn = blockIdx.y * 128;
    int wr = (wid >> 1) * 64, wc = (wid & 1) * 64;

    f32x4 acc[4][4] = {};

    for (int k0 = 0; k0 < K; k0 += 64) {
#pragma unroll
        for (int t = 0; t < 4; ++t) {
            int c = wid * 4 + t;
            int row = c * 8 + l8;
            int scol = ((l7 ^ (row & 7)) << 3);
            int ar = bm + row; if (ar > M - 1) ar = M - 1;
            __builtin_amdgcn_global_load_lds(
                (const GAS void*)(A + (size_t)ar * K + k0 + scol),
                (LAS void*)(&As[c * 512]), 16, 0, 0);
            int br = bn + row;
            __builtin_amdgcn_global_load_lds(
                (const GAS void*)(Bt + (size_t)br * K + k0 + scol),
                (LAS void*)(&Bs[c * 512]), 16, 0, 0);
        }
        __syncthreads();
#pragma unroll
        for (int kk = 0; kk < 2; ++kk) {
            bf16x8 af[4], bfv[4];
#pragma unroll
            for (int mi = 0; mi < 4; ++mi) {
                int row = wr + mi * 16 + l15;
                int kel = (kk * 32 + kgrp * 8) ^ ((row & 7) << 3);
                af[mi] = *(const bf16x8*)(&As[row * 64 + kel]);
            }
#pragma unroll
            for (int ni = 0; ni < 4; ++ni) {
                int row = wc + ni * 16 + l15;
                int kel = (kk * 32 + kgrp * 8) ^ ((row & 7) << 3);
                bfv[ni] = *(const bf16x8*)(&Bs[row * 64 + kel]);
            }
#pragma unroll
            for (int mi = 0; mi < 4; ++mi)
#pragma unroll
                for (int ni = 0; ni < 4; ++ni)
                    acc[mi][ni] = __builtin_amdgcn_mfma_f32_16x16x32_bf16(
                        af[mi], bfv[ni], acc[mi][ni], 0, 0, 0);
        }
        __syncthreads();
    }

    // ---- epilogue: wave-local 64x64 transpose in LDS, then 16B stores ----
    ushort_t* my = shmem + wid * 4096;
#pragma unroll
    for (int mi = 0; mi < 4; ++mi) {
#pragma unroll
        for (int ni = 0; ni < 4; ++ni) {
            int gcol = bn + wc + ni * 16 + l15;
#pragma unroll
            for (int r = 0; r < 4; ++r) {
                float v = acc[mi][ni][r];
                if (mode == 0) {
                    v += bias[gcol];
                    v = 1.0f / (1.0f + __expf(-v));
                }
                int lr = mi * 16 + kgrp * 4 + r;
                int lc = (ni * 16 + l15) ^ (kgrp << 3);
                my[lr * 64 + lc] = f2bf(v);
            }
        }
    }
#pragma unroll
    for (int it = 0; it < 8; ++it) {
        int r2 = (lane >> 3) + it * 8;
        int c2 = ((lane & 7) << 3) ^ (((r2 >> 2) & 3) << 3);
        bf16x8 vv = *(const bf16x8*)(&my[r2 * 64 + c2]);
        int grow = bm + wr + r2;
        if (grow < M) {
            int gc = bn + wc + (c2 ^ (((r2 >> 2) & 3) << 3));
            *(bf16x8*)(&Cout[(size_t)grow * N + gc]) = vv;
        }
    }
}

extern "C" void kernel_launch(void* const* d_in, const int* in_sizes, int n_in,
                              void* d_out, int out_size, void* d_ws, size_t ws_size,
                              hipStream_t stream) {
    const float* x        = (const float*)d_in[0];
    const int*   src      = (const int*)d_in[1];
    const int*   dst      = (const int*)d_in[2];
    const float* W_self1  = (const float*)d_in[3];
    const float* W_neigh1 = (const float*)d_in[4];
    const float* b1       = (const float*)d_in[5];
    const float* W_self2  = (const float*)d_in[6];
    const float* W_neigh2 = (const float*)d_in[7];
    const float* b2       = (const float*)d_in[8];
    float* out = (float*)d_out;

    // ---- workspace layout ----
    char* p = (char*)d_ws;
    auto alloc = [&](size_t bytes) { char* r = p; p += (bytes + 255) & ~(size_t)255; return r; };
    float*    invdeg   = (float*)alloc((size_t)N_NODES * 4);
    ushort_t* A1       = (ushort_t*)alloc((size_t)N_NODES * 256 * 2);  // [x | agg]
    ushort_t* h        = (ushort_t*)alloc((size_t)N_NODES * 256 * 2);
    ushort_t* u        = (ushort_t*)alloc((size_t)N_NODES * 256 * 2);  // [u_self | u_neigh]
    ushort_t* Wt1      = (ushort_t*)alloc((size_t)256 * 256 * 2);
    ushort_t* Wt2      = (ushort_t*)alloc((size_t)256 * 256 * 2);
    int* rowptr        = (int*)alloc((size_t)(N_NODES + 1) * 4);
    int* cursor        = (int*)alloc((size_t)N_NODES * 4);
    int* cnt           = (int*)alloc((size_t)N_NODES * 4);
    int* blockSums     = (int*)alloc(1024);
    int* csr_src       = (int*)alloc((size_t)N_EDGES * 4);

    const int SCAN_NB = (N_NODES + 1023) / 1024;

    // ---- converts ----
    convert_x_kernel<<<(N_NODES * F_IN / 4 + 255) / 256, 256, 0, stream>>>(
        x, A1, N_NODES * F_IN / 4);
    wtransK_kernel<<<(256 * 256 + 255) / 256, 256, 0, stream>>>(
        W_self1, W_neigh1, Wt1, 128, 256, 256);
    wtransN_kernel<<<(256 * 256 + 255) / 256, 256, 0, stream>>>(
        W_self2, W_neigh2, Wt2, 256, 128);

    // ---- CSR build ----
    hipMemsetAsync(cnt, 0, (size_t)N_NODES * sizeof(int), stream);
    deg_count_kernel<<<(N_EDGES + 255) / 256, 256, 0, stream>>>(dst, cnt, N_EDGES);
    invdeg_kernel<<<(N_NODES + 255) / 256, 256, 0, stream>>>(cnt, invdeg, N_NODES);
    scan1_kernel<<<SCAN_NB, 1024, 0, stream>>>(cnt, rowptr, blockSums, N_NODES);
    scan2_kernel<<<1, 128, 0, stream>>>(blockSums, SCAN_NB);
    scan3_kernel<<<SCAN_NB, 1024, 0, stream>>>(rowptr, cursor, blockSums, N_NODES);
    fill_csr_xcd_kernel<<<((N_EDGES + 255) / 256) * XBANDS, 256, 0, stream>>>(
        src, dst, cursor, csr_src, N_EDGES);

    // ---- layer 1: gather x -> A1[:,128:256], then h = sigmoid(A1 @ Wt1 + b1) ----
    gather16_kernel<0><<<(N_NODES + 3) / 4, 256, 0, stream>>>(
        A1, 256, rowptr, csr_src, invdeg, nullptr, 0, nullptr, A1 + 128, 256, N_NODES);
    {
        dim3 grid((N_NODES + 127) / 128, 2);
        gemm_mfma_kernel<<<grid, 256, 0, stream>>>(A1, Wt1, b1, h, N_NODES, 256, 256, 0);
    }

    // ---- layer 2: u = h @ [Ws2|Wn2] (one pass) ----
    {
        dim3 grid((N_NODES + 127) / 128, 2);
        gemm_mfma_kernel<<<grid, 256, 0, stream>>>(h, Wt2, nullptr, u, N_NODES, 256, 256, 1);
    }
    // ---- out = u_self + b2 + invdeg * gather(u_neigh) ----
    gather16_kernel<1><<<(N_NODES + 3) / 4, 256, 0, stream>>>(
        u + 128, 256, rowptr, csr_src, invdeg, u, 256, b2, out, 128, N_NODES);
}

// Round 9
// 363.363 us; speedup vs baseline: 1.0925x; 1.0925x over previous
//
#include <hip/hip_runtime.h>
#include <hip/hip_bf16.h>

#define N_NODES 100000
#define N_EDGES 1600000
#define F_IN 128
#define F_HID 256
#define F_OUT 128

typedef unsigned short ushort_t;
typedef __attribute__((ext_vector_type(4))) float f32x4;
typedef __attribute__((ext_vector_type(8))) short bf16x8;

#define GAS __attribute__((address_space(1)))
#define LAS __attribute__((address_space(3)))

__device__ __forceinline__ float bf2f(ushort_t u) {
    unsigned int x = ((unsigned int)u) << 16;
    return __builtin_bit_cast(float, x);
}
__device__ __forceinline__ ushort_t f2bf(float f) {
    unsigned int x = __builtin_bit_cast(unsigned int, f);
    unsigned int r = (x + 0x7fffu + ((x >> 16) & 1u)) >> 16;
    return (ushort_t)r;
}

// ---------------- CSR build ----------------
__global__ __launch_bounds__(256) void deg_count_kernel(const int* __restrict__ dst,
                                                        int* __restrict__ cnt, int n) {
    int i = blockIdx.x * 256 + threadIdx.x;
    if (i < n) atomicAdd(&cnt[__builtin_nontemporal_load(dst + i)], 1);
}

__global__ __launch_bounds__(256) void invdeg_kernel(const int* __restrict__ cnt,
                                                     float* __restrict__ inv, int n) {
    int i = blockIdx.x * 256 + threadIdx.x;
    if (i < n) inv[i] = 1.0f / fmaxf((float)cnt[i], 1.0f);
}

__global__ __launch_bounds__(1024) void scan1_kernel(const int* __restrict__ cnt,
                                                     int* __restrict__ rowptr,
                                                     int* __restrict__ blockSums, int n) {
    __shared__ int tmp[1024];
    int tid = threadIdx.x;
    int i = blockIdx.x * 1024 + tid;
    int v = (i < n) ? cnt[i] : 0;
    tmp[tid] = v;
    __syncthreads();
#pragma unroll
    for (int off = 1; off < 1024; off <<= 1) {
        int t = (tid >= off) ? tmp[tid - off] : 0;
        __syncthreads();
        tmp[tid] += t;
        __syncthreads();
    }
    if (i < n) rowptr[i] = tmp[tid] - v;
    if (tid == 1023) blockSums[blockIdx.x] = tmp[1023];
}

__global__ __launch_bounds__(128) void scan2_kernel(int* __restrict__ blockSums, int nb) {
    __shared__ int tmp[128];
    int tid = threadIdx.x;
    int v = (tid < nb) ? blockSums[tid] : 0;
    tmp[tid] = v;
    __syncthreads();
#pragma unroll
    for (int off = 1; off < 128; off <<= 1) {
        int t = (tid >= off) ? tmp[tid - off] : 0;
        __syncthreads();
        tmp[tid] += t;
        __syncthreads();
    }
    if (tid < nb) blockSums[tid] = tmp[tid] - v;
}

__global__ __launch_bounds__(1024) void scan3_kernel(int* __restrict__ rowptr,
                                                     const int* __restrict__ blockSums, int n) {
    int i = blockIdx.x * 1024 + threadIdx.x;
    if (i < n) rowptr[i] = rowptr[i] + blockSums[blockIdx.x];
    if (i == 0) rowptr[n] = N_EDGES;
}

// ---------------- 2-pass bucket sort fill ----------------
// Buckets = 256 consecutive dst nodes. Pass A bins packed (j,src) u32s into
// exact CSR-space bucket regions (block-level reservations -> ~84B write runs,
// no 10x line amplification). Pass B: one block per bucket places entries at
// rowptr[d]+rank; its entire 16KB write region lives in one XCD L2 and lines
// fill completely before eviction.
#define NBUCK ((N_NODES + 255) >> 8)  // 391
#define CHUNK 4096

__global__ __launch_bounds__(256) void bucket_init_kernel(const int* __restrict__ rowptr,
                                                          int* __restrict__ bcursor) {
    int b = blockIdx.x * 256 + threadIdx.x;
    if (b < NBUCK) bcursor[b] = rowptr[b << 8];
}

__global__ __launch_bounds__(256) void bin_edges_kernel(
    const int* __restrict__ src, const int* __restrict__ dst,
    int* __restrict__ bcursor, unsigned int* __restrict__ pairs, int n) {
    __shared__ int sdst[CHUNK];
    __shared__ int ssrc[CHUNK];
    __shared__ int hist[NBUCK];
    __shared__ int resv[NBUCK];
    int tid = threadIdx.x;
    int e0 = blockIdx.x * CHUNK;
    int cnt = n - e0; if (cnt > CHUNK) cnt = CHUNK;
    for (int b = tid; b < NBUCK; b += 256) hist[b] = 0;
    __syncthreads();
    for (int i = tid; i < cnt; i += 256) {
        int d = __builtin_nontemporal_load(dst + e0 + i);
        int s = __builtin_nontemporal_load(src + e0 + i);
        sdst[i] = d;
        ssrc[i] = s;
        atomicAdd(&hist[d >> 8], 1);
    }
    __syncthreads();
    for (int b = tid; b < NBUCK; b += 256) {
        int h = hist[b];
        resv[b] = h ? atomicAdd(&bcursor[b], h) : 0;
        hist[b] = 0;  // reuse as local offset
    }
    __syncthreads();
    for (int i = tid; i < cnt; i += 256) {
        int d = sdst[i], s = ssrc[i];
        int b = d >> 8;
        int off = atomicAdd(&hist[b], 1);
        pairs[resv[b] + off] = ((unsigned)(d & 255) << 17) | (unsigned)s;
    }
}

__global__ __launch_bounds__(256) void sort_bucket_kernel(
    const unsigned int* __restrict__ pairs, const int* __restrict__ rowptr,
    int* __restrict__ csr_src, int nNodes) {
    __shared__ int lcnt[256];
    __shared__ int lrp[257];
    int tid = threadIdx.x;
    int base = blockIdx.x << 8;
    int nn = nNodes - base; if (nn > 256) nn = 256;
    if (tid < nn) { lrp[tid] = rowptr[base + tid]; lcnt[tid] = 0; }
    if (tid == 0) lrp[nn] = rowptr[base + nn];
    __syncthreads();
    int e0 = lrp[0], e1 = lrp[nn];
    for (int i = e0 + tid; i < e1; i += 256) {
        unsigned v = pairs[i];
        int s = (int)(v & 0x1FFFFu);
        int j = (int)(v >> 17);
        int off = atomicAdd(&lcnt[j], 1);
        csr_src[lrp[j] + off] = s;
    }
}

// ---------------- fp32 -> bf16 converts ----------------
__global__ __launch_bounds__(256) void convert_x_kernel(const float* __restrict__ x,
                                                        ushort_t* __restrict__ A1, int n4) {
    int i = blockIdx.x * 256 + threadIdx.x;
    if (i >= n4) return;
    int e = i * 4;
    int row = e >> 7;
    int col = e & 127;
    f32x4 v = __builtin_nontemporal_load((const f32x4*)(x + (size_t)row * F_IN + col));
    ushort4 o;
    o.x = f2bf(v.x); o.y = f2bf(v.y); o.z = f2bf(v.z); o.w = f2bf(v.w);
    *(ushort4*)(A1 + (size_t)row * 256 + col) = o;
}

// Wt[n][k] = bf16( k<Kx ? W1[k][n] : W2[k-Kx][n] )  -- stack along K
__global__ __launch_bounds__(256) void wtransK_kernel(const float* __restrict__ W1,
                                                      const float* __restrict__ W2,
                                                      ushort_t* __restrict__ Wt,
                                                      int Kx, int Ktot, int N) {
    int i = blockIdx.x * 256 + threadIdx.x;
    if (i >= N * Ktot) return;
    int n = i / Ktot, k = i - n * Ktot;
    float v = (k < Kx) ? W1[(size_t)k * N + n] : W2[(size_t)(k - Kx) * N + n];
    Wt[(size_t)n * Ktot + k] = f2bf(v);
}

// Wt[n][k]: n<Nh -> Wa[k][n], else Wb[k][n-Nh]  -- stack along N
__global__ __launch_bounds__(256) void wtransN_kernel(const float* __restrict__ Wa,
                                                      const float* __restrict__ Wb,
                                                      ushort_t* __restrict__ Wt,
                                                      int K, int Nh) {
    int i = blockIdx.x * 256 + threadIdx.x;
    if (i >= 2 * Nh * K) return;
    int n = i / K, k = i - n * K;
    const float* W = (n < Nh) ? Wa : Wb;
    int nn = (n < Nh) ? n : n - Nh;
    Wt[(size_t)n * K + k] = f2bf(W[(size_t)k * Nh + nn]);
}

// ---------------- 16-lane-per-edge gather, 4 edges per group-iter ----------------
#define ACC8(v)                                                     \
    acc[0] += bf2f((ushort_t)((v).x & 0xffffu));                    \
    acc[1] += bf2f((ushort_t)((v).x >> 16));                        \
    acc[2] += bf2f((ushort_t)((v).y & 0xffffu));                    \
    acc[3] += bf2f((ushort_t)((v).y >> 16));                        \
    acc[4] += bf2f((ushort_t)((v).z & 0xffffu));                    \
    acc[5] += bf2f((ushort_t)((v).z >> 16));                        \
    acc[6] += bf2f((ushort_t)((v).w & 0xffffu));                    \
    acc[7] += bf2f((ushort_t)((v).w >> 16));

template <int MODE>
__global__ __launch_bounds__(256) void gather16_kernel(
    const ushort_t* __restrict__ H, int ldh,
    const int* __restrict__ rowptr, const int* __restrict__ csr_src,
    const float* __restrict__ invdeg,
    const ushort_t* __restrict__ uself, int ldu,
    const float* __restrict__ bias,
    void* __restrict__ outp, int ldo, int nNodes) {
    int lane = threadIdx.x & 63;
    int node = blockIdx.x * 4 + (threadIdx.x >> 6);
    if (node >= nNodes) return;
    int grp = lane >> 4, sub = lane & 15;
    int start = rowptr[node], end = rowptr[node + 1];
    const size_t cofs = (size_t)sub * 8;
    float acc[8] = {};
    // 16 edges in flight per wave: 4 groups x 4 predicated loads
    for (int e = start + grp; e < end; e += 16) {
        int s0 = csr_src[e];
        uint4 v0 = *(const uint4*)(H + (size_t)s0 * ldh + cofs);
        bool p1 = (e + 4) < end;
        int s1 = p1 ? csr_src[e + 4] : s0;
        uint4 v1 = *(const uint4*)(H + (size_t)s1 * ldh + cofs);
        bool p2 = (e + 8) < end;
        int s2 = p2 ? csr_src[e + 8] : s0;
        uint4 v2 = *(const uint4*)(H + (size_t)s2 * ldh + cofs);
        bool p3 = (e + 12) < end;
        int s3 = p3 ? csr_src[e + 12] : s0;
        uint4 v3 = *(const uint4*)(H + (size_t)s3 * ldh + cofs);
        ACC8(v0);
        if (p1) { ACC8(v1); }
        if (p2) { ACC8(v2); }
        if (p3) { ACC8(v3); }
    }
#pragma unroll
    for (int j = 0; j < 8; ++j) {
        acc[j] += __shfl_xor(acc[j], 16);
        acc[j] += __shfl_xor(acc[j], 32);
    }
    if (grp == 0) {
        float sc = invdeg[node];
        if (MODE == 0) {
            uint4 o;
            o.x = (unsigned)f2bf(acc[0] * sc) | ((unsigned)f2bf(acc[1] * sc) << 16);
            o.y = (unsigned)f2bf(acc[2] * sc) | ((unsigned)f2bf(acc[3] * sc) << 16);
            o.z = (unsigned)f2bf(acc[4] * sc) | ((unsigned)f2bf(acc[5] * sc) << 16);
            o.w = (unsigned)f2bf(acc[6] * sc) | ((unsigned)f2bf(acc[7] * sc) << 16);
            *(uint4*)((ushort_t*)outp + (size_t)node * ldo + cofs) = o;
        } else {
            uint4 us = *(const uint4*)(uself + (size_t)node * ldu + cofs);
            f32x4 o0, o1;
            o0.x = acc[0] * sc + bf2f((ushort_t)(us.x & 0xffffu)) + bias[cofs + 0];
            o0.y = acc[1] * sc + bf2f((ushort_t)(us.x >> 16)) + bias[cofs + 1];
            o0.z = acc[2] * sc + bf2f((ushort_t)(us.y & 0xffffu)) + bias[cofs + 2];
            o0.w = acc[3] * sc + bf2f((ushort_t)(us.y >> 16)) + bias[cofs + 3];
            o1.x = acc[4] * sc + bf2f((ushort_t)(us.z & 0xffffu)) + bias[cofs + 4];
            o1.y = acc[5] * sc + bf2f((ushort_t)(us.z >> 16)) + bias[cofs + 5];
            o1.z = acc[6] * sc + bf2f((ushort_t)(us.w & 0xffffu)) + bias[cofs + 6];
            o1.w = acc[7] * sc + bf2f((ushort_t)(us.w >> 16)) + bias[cofs + 7];
            float* op = (float*)outp + (size_t)node * ldo + cofs;
            __builtin_nontemporal_store(o0, (f32x4*)op);
            __builtin_nontemporal_store(o1, (f32x4*)(op + 4));
        }
    }
}

// ---------------- bf16 MFMA GEMM ----------------
// C = A[M][K] @ Bt[N][K]^T ; 128x128 tile, 4 waves x (64x64), BK=64.
// mode 0: bf16 out, +bias, sigmoid ; mode 1: bf16 out
// Epilogue: per-wave LDS transpose (XOR-swizzled, conflict-free) -> b128 stores.
__global__ __launch_bounds__(256) void gemm_mfma_kernel(
    const ushort_t* __restrict__ A,
    const ushort_t* __restrict__ Bt,
    const float* __restrict__ bias,
    ushort_t* __restrict__ Cout,
    int M, int N, int K, int mode) {
    __shared__ ushort_t shmem[2 * 128 * 64];  // staging As|Bs; reused by epilogue
    ushort_t* As = shmem;
    ushort_t* Bs = shmem + 128 * 64;
    int tid = threadIdx.x;
    int lane = tid & 63, wid = tid >> 6;
    int l15 = lane & 15, kgrp = lane >> 4, l7 = lane & 7, l8 = lane >> 3;
    int bm = blockIdx.x * 128, bn = blockIdx.y * 128;
    int wr = (wid >> 1) * 64, wc = (wid & 1) * 64;

    f32x4 acc[4][4] = {};

    for (int k0 = 0; k0 < K; k0 += 64) {
#pragma unroll
        for (int t = 0; t < 4; ++t) {
            int c = wid * 4 + t;
            int row = c * 8 + l8;
            int scol = ((l7 ^ (row & 7)) << 3);
            int ar = bm + row; if (ar > M - 1) ar = M - 1;
            __builtin_amdgcn_global_load_lds(
                (const GAS void*)(A + (size_t)ar * K + k0 + scol),
                (LAS void*)(&As[c * 512]), 16, 0, 0);
            int br = bn + row;
            __builtin_amdgcn_global_load_lds(
                (const GAS void*)(Bt + (size_t)br * K + k0 + scol),
                (LAS void*)(&Bs[c * 512]), 16, 0, 0);
        }
        __syncthreads();
#pragma unroll
        for (int kk = 0; kk < 2; ++kk) {
            bf16x8 af[4], bfv[4];
#pragma unroll
            for (int mi = 0; mi < 4; ++mi) {
                int row = wr + mi * 16 + l15;
                int kel = (kk * 32 + kgrp * 8) ^ ((row & 7) << 3);
                af[mi] = *(const bf16x8*)(&As[row * 64 + kel]);
            }
#pragma unroll
            for (int ni = 0; ni < 4; ++ni) {
                int row = wc + ni * 16 + l15;
                int kel = (kk * 32 + kgrp * 8) ^ ((row & 7) << 3);
                bfv[ni] = *(const bf16x8*)(&Bs[row * 64 + kel]);
            }
#pragma unroll
            for (int mi = 0; mi < 4; ++mi)
#pragma unroll
                for (int ni = 0; ni < 4; ++ni)
                    acc[mi][ni] = __builtin_amdgcn_mfma_f32_16x16x32_bf16(
                        af[mi], bfv[ni], acc[mi][ni], 0, 0, 0);
        }
        __syncthreads();
    }

    // ---- epilogue: wave-local 64x64 transpose in LDS, then 16B stores ----
    ushort_t* my = shmem + wid * 4096;
#pragma unroll
    for (int mi = 0; mi < 4; ++mi) {
#pragma unroll
        for (int ni = 0; ni < 4; ++ni) {
            int gcol = bn + wc + ni * 16 + l15;
#pragma unroll
            for (int r = 0; r < 4; ++r) {
                float v = acc[mi][ni][r];
                if (mode == 0) {
                    v += bias[gcol];
                    v = 1.0f / (1.0f + __expf(-v));
                }
                int lr = mi * 16 + kgrp * 4 + r;
                int lc = (ni * 16 + l15) ^ (kgrp << 3);
                my[lr * 64 + lc] = f2bf(v);
            }
        }
    }
#pragma unroll
    for (int it = 0; it < 8; ++it) {
        int r2 = (lane >> 3) + it * 8;
        int c2 = ((lane & 7) << 3) ^ (((r2 >> 2) & 3) << 3);
        bf16x8 vv = *(const bf16x8*)(&my[r2 * 64 + c2]);
        int grow = bm + wr + r2;
        if (grow < M) {
            int gc = bn + wc + (c2 ^ (((r2 >> 2) & 3) << 3));
            *(bf16x8*)(&Cout[(size_t)grow * N + gc]) = vv;
        }
    }
}

extern "C" void kernel_launch(void* const* d_in, const int* in_sizes, int n_in,
                              void* d_out, int out_size, void* d_ws, size_t ws_size,
                              hipStream_t stream) {
    const float* x        = (const float*)d_in[0];
    const int*   src      = (const int*)d_in[1];
    const int*   dst      = (const int*)d_in[2];
    const float* W_self1  = (const float*)d_in[3];
    const float* W_neigh1 = (const float*)d_in[4];
    const float* b1       = (const float*)d_in[5];
    const float* W_self2  = (const float*)d_in[6];
    const float* W_neigh2 = (const float*)d_in[7];
    const float* b2       = (const float*)d_in[8];
    float* out = (float*)d_out;

    // ---- workspace layout ----
    char* p = (char*)d_ws;
    auto alloc = [&](size_t bytes) { char* r = p; p += (bytes + 255) & ~(size_t)255; return r; };
    float*    invdeg   = (float*)alloc((size_t)N_NODES * 4);
    ushort_t* A1       = (ushort_t*)alloc((size_t)N_NODES * 256 * 2);  // [x | agg]
    ushort_t* h        = (ushort_t*)alloc((size_t)N_NODES * 256 * 2);
    ushort_t* u        = (ushort_t*)alloc((size_t)N_NODES * 256 * 2);  // [u_self | u_neigh]
    ushort_t* Wt1      = (ushort_t*)alloc((size_t)256 * 256 * 2);
    ushort_t* Wt2      = (ushort_t*)alloc((size_t)256 * 256 * 2);
    int* rowptr        = (int*)alloc((size_t)(N_NODES + 1) * 4);
    int* cnt           = (int*)alloc((size_t)N_NODES * 4);
    int* blockSums     = (int*)alloc(1024);
    int* bcursor       = (int*)alloc((size_t)NBUCK * 4);
    unsigned int* pairs= (unsigned int*)alloc((size_t)N_EDGES * 4);
    int* csr_src       = (int*)alloc((size_t)N_EDGES * 4);

    const int SCAN_NB = (N_NODES + 1023) / 1024;

    // ---- converts ----
    convert_x_kernel<<<(N_NODES * F_IN / 4 + 255) / 256, 256, 0, stream>>>(
        x, A1, N_NODES * F_IN / 4);
    wtransK_kernel<<<(256 * 256 + 255) / 256, 256, 0, stream>>>(
        W_self1, W_neigh1, Wt1, 128, 256, 256);
    wtransN_kernel<<<(256 * 256 + 255) / 256, 256, 0, stream>>>(
        W_self2, W_neigh2, Wt2, 256, 128);

    // ---- CSR build: deg -> scan -> bucket-binned sort ----
    hipMemsetAsync(cnt, 0, (size_t)N_NODES * sizeof(int), stream);
    deg_count_kernel<<<(N_EDGES + 255) / 256, 256, 0, stream>>>(dst, cnt, N_EDGES);
    invdeg_kernel<<<(N_NODES + 255) / 256, 256, 0, stream>>>(cnt, invdeg, N_NODES);
    scan1_kernel<<<SCAN_NB, 1024, 0, stream>>>(cnt, rowptr, blockSums, N_NODES);
    scan2_kernel<<<1, 128, 0, stream>>>(blockSums, SCAN_NB);
    scan3_kernel<<<SCAN_NB, 1024, 0, stream>>>(rowptr, blockSums, N_NODES);
    bucket_init_kernel<<<(NBUCK + 255) / 256, 256, 0, stream>>>(rowptr, bcursor);
    bin_edges_kernel<<<(N_EDGES + CHUNK - 1) / CHUNK, 256, 0, stream>>>(
        src, dst, bcursor, pairs, N_EDGES);
    sort_bucket_kernel<<<NBUCK, 256, 0, stream>>>(pairs, rowptr, csr_src, N_NODES);

    // ---- layer 1: gather x -> A1[:,128:256], then h = sigmoid(A1 @ Wt1 + b1) ----
    gather16_kernel<0><<<(N_NODES + 3) / 4, 256, 0, stream>>>(
        A1, 256, rowptr, csr_src, invdeg, nullptr, 0, nullptr, A1 + 128, 256, N_NODES);
    {
        dim3 grid((N_NODES + 127) / 128, 2);
        gemm_mfma_kernel<<<grid, 256, 0, stream>>>(A1, Wt1, b1, h, N_NODES, 256, 256, 0);
    }

    // ---- layer 2: u = h @ [Ws2|Wn2] (one pass) ----
    {
        dim3 grid((N_NODES + 127) / 128, 2);
        gemm_mfma_kernel<<<grid, 256, 0, stream>>>(h, Wt2, nullptr, u, N_NODES, 256, 256, 1);
    }
    // ---- out = u_self + b2 + invdeg * gather(u_neigh) ----
    gather16_kernel<1><<<(N_NODES + 3) / 4, 256, 0, stream>>>(
        u + 128, 256, rowptr, csr_src, invdeg, u, 256, b2, out, 128, N_NODES);
}